// Round 5
// baseline (106.702 us; speedup 1.0000x reference)
//
#include <hip/hip_runtime.h>
#include <hip/hip_bf16.h>

#define NH 4
#define HD 32
#define PAD 3
#define HW 56
#define NPIX (8*HW*HW)          // 25088 pixels
#define SCALE 0.17677669529663687f

// ---------------- workspace layout (bytes) ----------------
// qs    : f32  [8][4][56][56][32]   12,845,056
// kbuf  : bf16 [8][4][56][56][32]    6,422,528
// vbuf  : bf16 [8][4][56][56][32]    6,422,528
// xh/xl : bf16 [25088][128]          6,422,528 each   (reused as attn_h/attn_l)
// W splits: qkv hi/lo 98,304 each; proj hi/lo 32,768 each
#define QS_OFF   0
#define K_OFF    12845056
#define V_OFF    (K_OFF + 6422528)
#define XH_OFF   (V_OFF + 6422528)      // = attn_h after natt
#define XL_OFF   (XH_OFF + 6422528)     // = attn_l after natt
#define WQH_OFF  (XL_OFF + 6422528)
#define WQL_OFF  (WQH_OFF + 98304)
#define WPH_OFF  (WQL_OFF + 98304)
#define WPL_OFF  (WPH_OFF + 32768)

typedef __attribute__((ext_vector_type(8))) short short8v;
typedef __attribute__((ext_vector_type(4))) float f32x4;

__device__ __forceinline__ unsigned short f2b(float x) {       // f32 -> bf16 bits, RNE
    unsigned u = __float_as_uint(x);
    unsigned r = (u + 0x7fffu + ((u >> 16) & 1u)) >> 16;
    return (unsigned short)r;
}
__device__ __forceinline__ float b2f(unsigned short s) { return __uint_as_float((unsigned)s << 16); }

// quad (4-lane) sum via DPP quad_perm: xor1 = 0xB1, xor2 = 0x4E. VALU-only.
__device__ __forceinline__ float quad_sum(float x) {
    x += __int_as_float(__builtin_amdgcn_update_dpp(0, __float_as_int(x), 0xB1, 0xF, 0xF, true));
    x += __int_as_float(__builtin_amdgcn_update_dpp(0, __float_as_int(x), 0x4E, 0xF, 0xF, true));
    return x;
}

// ---------------------------------------------------------------------------
// Pre-split: f32 -> (hi, lo) bf16 pairs for x, W_qkv, W_proj. One dispatch.
// ---------------------------------------------------------------------------
__global__ __launch_bounds__(256) void split_k(
    const float* __restrict__ x, const float* __restrict__ wq, const float* __restrict__ wp,
    unsigned short* __restrict__ xh, unsigned short* __restrict__ xl,
    unsigned short* __restrict__ wqh, unsigned short* __restrict__ wql,
    unsigned short* __restrict__ wph, unsigned short* __restrict__ wpl)
{
    int idx = blockIdx.x * 256 + threadIdx.x;
    if (idx >= 819200) return;
    const float* src; unsigned short *dh, *dl; int off;
    if (idx < 802816)      { src = x;  dh = xh;  dl = xl;  off = idx; }
    else if (idx < 815104) { src = wq; dh = wqh; dl = wql; off = idx - 802816; }
    else                   { src = wp; dh = wph; dl = wpl; off = idx - 815104; }
    float4 v = ((const float4*)src)[off];
    ushort4 h, l;
    h.x = f2b(v.x); l.x = f2b(v.x - b2f(h.x));
    h.y = f2b(v.y); l.y = f2b(v.y - b2f(h.y));
    h.z = f2b(v.z); l.z = f2b(v.z - b2f(h.z));
    h.w = f2b(v.w); l.w = f2b(v.w - b2f(h.w));
    ((ushort4*)dh)[off] = h;
    ((ushort4*)dl)[off] = l;
}

// ---------------------------------------------------------------------------
// MFMA GEMM (bf16x2 split): unchanged from round 4 (passing, absmax 2.4e-4).
// ---------------------------------------------------------------------------
template <int SELQKV>
__global__ __launch_bounds__(256, 2) void gemm_mfma(
    const unsigned short* __restrict__ Ah, const unsigned short* __restrict__ Al,
    const unsigned short* __restrict__ Bh, const unsigned short* __restrict__ Bl,
    const float* __restrict__ bias,
    float* __restrict__ outq, unsigned short* __restrict__ outk,
    unsigned short* __restrict__ outv, float* __restrict__ outp)
{
    __shared__ unsigned short sAh[64 * 128];
    __shared__ unsigned short sAl[64 * 128];
    __shared__ unsigned short sBh[64 * 128];
    __shared__ unsigned short sBl[64 * 128];

    const int tid = threadIdx.x;
    const int m0 = blockIdx.x * 64;
    const int n0 = blockIdx.y * 64;

#pragma unroll
    for (int it = 0; it < 4; ++it) {
        int chunk = it * 256 + tid;          // 0..1023
        int row = chunk >> 4, c16 = chunk & 15;
        int byte = (row * 256 + c16 * 16) ^ ((row & 7) << 4);
        size_t ga = (size_t)(m0 + row) * 128 + c16 * 8;
        size_t gb = (size_t)(n0 + row) * 128 + c16 * 8;
        *(uint4*)((char*)sAh + byte) = *(const uint4*)(Ah + ga);
        *(uint4*)((char*)sAl + byte) = *(const uint4*)(Al + ga);
        *(uint4*)((char*)sBh + byte) = *(const uint4*)(Bh + gb);
        *(uint4*)((char*)sBl + byte) = *(const uint4*)(Bl + gb);
    }
    __syncthreads();

    const int lane = tid & 63;
    const int w  = tid >> 6;
    const int wr = w >> 1, wc = w & 1;       // 2x2 waves -> 64x64
    const int fr  = lane & 15;
    const int kqb = (lane >> 4) * 16;        // k byte offset within 64B group

    f32x4 acc[2][2];
#pragma unroll
    for (int i = 0; i < 2; ++i)
#pragma unroll
        for (int j = 0; j < 2; ++j) acc[i][j] = (f32x4){0.f, 0.f, 0.f, 0.f};

#pragma unroll
    for (int ks = 0; ks < 4; ++ks) {
        short8v ah[2], al[2], bh[2], bl[2];
#pragma unroll
        for (int mi = 0; mi < 2; ++mi) {
            int row = wr * 32 + mi * 16 + fr;
            int byte = (row * 256 + ks * 64 + kqb) ^ ((row & 7) << 4);
            ah[mi] = *(const short8v*)((const char*)sAh + byte);
            al[mi] = *(const short8v*)((const char*)sAl + byte);
        }
#pragma unroll
        for (int ni = 0; ni < 2; ++ni) {
            int row = wc * 32 + ni * 16 + fr;
            int byte = (row * 256 + ks * 64 + kqb) ^ ((row & 7) << 4);
            bh[ni] = *(const short8v*)((const char*)sBh + byte);
            bl[ni] = *(const short8v*)((const char*)sBl + byte);
        }
#pragma unroll
        for (int mi = 0; mi < 2; ++mi)
#pragma unroll
            for (int ni = 0; ni < 2; ++ni) {
                acc[mi][ni] = __builtin_amdgcn_mfma_f32_16x16x32_bf16(ah[mi], bh[ni], acc[mi][ni], 0, 0, 0);
                acc[mi][ni] = __builtin_amdgcn_mfma_f32_16x16x32_bf16(ah[mi], bl[ni], acc[mi][ni], 0, 0, 0);
                acc[mi][ni] = __builtin_amdgcn_mfma_f32_16x16x32_bf16(al[mi], bh[ni], acc[mi][ni], 0, 0, 0);
            }
    }

    const int cl = lane & 15;
    const int rq = lane >> 4;

#pragma unroll
    for (int mi = 0; mi < 2; ++mi) {
#pragma unroll
        for (int reg = 0; reg < 4; ++reg) {
            int m = m0 + wr * 32 + mi * 16 + rq * 4 + reg;
            if constexpr (SELQKV) {
                int b = m / 3136;
                int r = m - b * 3136;
                int y = r / 56;
                int x = r - y * 56;
#pragma unroll
                for (int ni = 0; ni < 2; ++ni) {
                    int nn = n0 + wc * 32 + ni * 16 + cl;   // 0..383
                    float val = acc[mi][ni][reg] + bias[nn];
                    int sel = nn >> 7;                      // 0=q 1=k 2=v
                    int nl = nn & 127;
                    int h = nl >> 5, d = nl & 31;
                    size_t oi = ((size_t)((b * NH + h) * 3136) + y * 56 + x) * 32 + d;
                    if (sel == 0)      outq[oi] = val * SCALE;
                    else if (sel == 1) outk[oi] = f2b(val);
                    else               outv[oi] = f2b(val);
                }
            } else {
#pragma unroll
                for (int ni = 0; ni < 2; ++ni) {
                    int nn = n0 + wc * 32 + ni * 16 + cl;
                    outp[(size_t)m * 128 + nn] = acc[mi][ni][reg] + bias[nn];
                }
            }
        }
    }
}

// ---------------------------------------------------------------------------
// Neighborhood attention v4: MFMA.  Block = (b, head, 8x8 q-tile), 256 thr.
// Halo 14x14 = 196 keys, padded to 224.  Phases:
//  P0 stage: K [224][40] bf16 (80B rows), V^T [32][232], Q hi/lo [64][40],
//            rpb[49].  OOB-in-halo zero-staged (reference zero-pad semantics),
//            pad rows/cols zeroed (no NaN into PV).
//  P1 QK^T:  S[q][key] = (Qh+Ql)*K via 2 mfma per 16x16 frag -> S LDS f32.
//  P2 softmax: 4 thr/q, 56 keys each (part*56 % 14 == 0 -> decode is
//            compile-time), window mask + rpb, exp, DPP quad-sum.
//            P = e/l written hi/lo bf16 into the S region (barrier-separated).
//  P3 PV:    out = (Ph+Pl)*V^T via mfma, K=224 in 7 steps.
//  P4: write attn hi/lo bf16.
// LDS total ~102.6 KB -> 1 block/CU.
// ---------------------------------------------------------------------------
__global__ __launch_bounds__(256) void natt_k(
    const float* __restrict__ qs, const unsigned short* __restrict__ kb,
    const unsigned short* __restrict__ vb, const float* __restrict__ rpb,
    unsigned short* __restrict__ attn_h, unsigned short* __restrict__ attn_l)
{
    __shared__ unsigned short Kl[224 * 40];   // 17920 B
    __shared__ unsigned short Vt[32 * 232];   // 14848 B
    __shared__ unsigned short Qh[64 * 40];    //  5120 B
    __shared__ unsigned short Ql[64 * 40];    //  5120 B
    __shared__ float SP[14848];               // 59392 B: S[64][228] f32, then Ph/Pl
    __shared__ float rp[49];

    unsigned short* Ph = (unsigned short*)SP;
    unsigned short* Pl = Ph + 64 * 232;

    const int tid = threadIdx.x;
    const int b = blockIdx.z, h = blockIdx.y;
    const int tyy = blockIdx.x / 7, txx = blockIdx.x - tyy * 7;
    const int y0 = tyy * 8, x0 = txx * 8;
    const int bh = b * NH + h;

    if (tid < 49) rp[tid] = rpb[h * 49 + tid];

    // ---- P0: stage K, V^T (and zero pads) ----
    const uint4* kg = (const uint4*)kb;  // 4 uint4 per pixel (32 bf16)
    const uint4* vg = (const uint4*)vb;
    for (int idx = tid; idx < 896; idx += 256) {    // 224 pix * 4 chunks
        int pix = idx >> 2, c = idx & 3;
        int hy = pix / 14;
        int hx = pix - hy * 14;
        int y = y0 + hy - PAD;
        int x = x0 + hx - PAD;
        uint4 kz = make_uint4(0u, 0u, 0u, 0u);
        uint4 vz = make_uint4(0u, 0u, 0u, 0u);
        if (pix < 196 && (unsigned)y < 56u && (unsigned)x < 56u) {
            int g = ((bh * 3136) + y * 56 + x) * 4 + c;
            kz = kg[g];
            vz = vg[g];
        }
        *(uint4*)((char*)Kl + pix * 80 + c * 16) = kz;
        int d0 = c * 8;
        Vt[(d0 + 0) * 232 + pix] = (unsigned short)(vz.x & 0xffffu);
        Vt[(d0 + 1) * 232 + pix] = (unsigned short)(vz.x >> 16);
        Vt[(d0 + 2) * 232 + pix] = (unsigned short)(vz.y & 0xffffu);
        Vt[(d0 + 3) * 232 + pix] = (unsigned short)(vz.y >> 16);
        Vt[(d0 + 4) * 232 + pix] = (unsigned short)(vz.z & 0xffffu);
        Vt[(d0 + 5) * 232 + pix] = (unsigned short)(vz.z >> 16);
        Vt[(d0 + 6) * 232 + pix] = (unsigned short)(vz.w & 0xffffu);
        Vt[(d0 + 7) * 232 + pix] = (unsigned short)(vz.w >> 16);
    }
    // stage Q (f32 -> hi/lo bf16)
    for (int idx = tid; idx < 512; idx += 256) {    // 64 pix * 8 float4
        int qp = idx >> 3, c4 = idx & 7;
        int gy = y0 + (qp >> 3), gx = x0 + (qp & 7);
        float4 f = *(const float4*)(qs + ((size_t)(bh * 3136) + gy * 56 + gx) * 32 + c4 * 4);
        ushort4 hh, ll;
        hh.x = f2b(f.x); ll.x = f2b(f.x - b2f(hh.x));
        hh.y = f2b(f.y); ll.y = f2b(f.y - b2f(hh.y));
        hh.z = f2b(f.z); ll.z = f2b(f.z - b2f(hh.z));
        hh.w = f2b(f.w); ll.w = f2b(f.w - b2f(hh.w));
        *(ushort4*)(&Qh[qp * 40 + c4 * 4]) = hh;
        *(ushort4*)(&Ql[qp * 40 + c4 * 4]) = ll;
    }
    __syncthreads();

    const int lane = tid & 63;
    const int w  = tid >> 6;          // wave = M-frag (q rows 16w..16w+15)
    const int g  = lane >> 4;
    const int cc = lane & 15;

    // ---- P1: QK^T -> S LDS ----
    {
        short8v qah = *(const short8v*)(&Qh[(16 * w + cc) * 40 + 8 * g]);
        short8v qal = *(const short8v*)(&Ql[(16 * w + cc) * 40 + 8 * g]);
#pragma unroll
        for (int nf = 0; nf < 14; ++nf) {
            short8v kf = *(const short8v*)(&Kl[(16 * nf + cc) * 40 + 8 * g]);
            f32x4 a = (f32x4){0.f, 0.f, 0.f, 0.f};
            a = __builtin_amdgcn_mfma_f32_16x16x32_bf16(qal, kf, a, 0, 0, 0);
            a = __builtin_amdgcn_mfma_f32_16x16x32_bf16(qah, kf, a, 0, 0, 0);
#pragma unroll
            for (int r = 0; r < 4; ++r)
                SP[(16 * w + 4 * g + r) * 228 + 16 * nf + cc] = a[r];
        }
    }
    __syncthreads();

    // ---- P2: softmax (4 threads per q, 56 keys each) ----
    {
        const int q = tid >> 2, part = tid & 3;
        const int qy = q >> 3, qx = q & 7;
        float e[56];
        float l = 0.f;
        const float* srow = SP + q * 228 + part * 56;
#pragma unroll
        for (int j = 0; j < 14; ++j) {
            float4 f = *(const float4*)(srow + j * 4);
            float fv[4] = {f.x, f.y, f.z, f.w};
#pragma unroll
            for (int u = 0; u < 4; ++u) {
                int i = j * 4 + u;                  // compile-time
                int kidx = part * 56 + i;
                int hy = part * 4 + (i / 14);       // part*56 % 14 == 0
                int hx = i % 14;
                int dy = hy - qy, dx = hx - qx;
                bool ok = ((unsigned)dy < 7u) && ((unsigned)dx < 7u) && (kidx < 196);
                int rr = ok ? (dy * 7 + dx) : 0;
                float ev = ok ? __expf(fv[u] + rp[rr]) : 0.f;
                e[i] = ev;
                l += ev;
            }
        }
        l = quad_sum(l);
        float rl = 1.0f / l;
        __syncthreads();                 // all S reads done before P overwrites
#pragma unroll
        for (int j = 0; j < 28; ++j) {
            float p0 = e[2 * j] * rl;
            float p1 = e[2 * j + 1] * rl;
            unsigned short h0 = f2b(p0), h1 = f2b(p1);
            unsigned short l0 = f2b(p0 - b2f(h0)), l1 = f2b(p1 - b2f(h1));
            int o = q * 232 + part * 56 + 2 * j;
            *(unsigned*)(&Ph[o]) = (unsigned)h0 | ((unsigned)h1 << 16);
            *(unsigned*)(&Pl[o]) = (unsigned)l0 | ((unsigned)l1 << 16);
        }
    }
    __syncthreads();

    // ---- P3: PV ----
    f32x4 o0 = (f32x4){0.f, 0.f, 0.f, 0.f};
    f32x4 o1 = (f32x4){0.f, 0.f, 0.f, 0.f};
#pragma unroll
    for (int ks = 0; ks < 7; ++ks) {
        short8v pah = *(const short8v*)(&Ph[(16 * w + cc) * 232 + ks * 32 + 8 * g]);
        short8v pal = *(const short8v*)(&Pl[(16 * w + cc) * 232 + ks * 32 + 8 * g]);
        short8v v0 = *(const short8v*)(&Vt[cc * 232 + ks * 32 + 8 * g]);
        short8v v1 = *(const short8v*)(&Vt[(16 + cc) * 232 + ks * 32 + 8 * g]);
        o0 = __builtin_amdgcn_mfma_f32_16x16x32_bf16(pal, v0, o0, 0, 0, 0);
        o0 = __builtin_amdgcn_mfma_f32_16x16x32_bf16(pah, v0, o0, 0, 0, 0);
        o1 = __builtin_amdgcn_mfma_f32_16x16x32_bf16(pal, v1, o1, 0, 0, 0);
        o1 = __builtin_amdgcn_mfma_f32_16x16x32_bf16(pah, v1, o1, 0, 0, 0);
    }

    // ---- P4: write attn hi/lo ----
#pragma unroll
    for (int r = 0; r < 4; ++r) {
        int q2 = 16 * w + 4 * g + r;
        int gy = y0 + (q2 >> 3), gx = x0 + (q2 & 7);
        size_t base = ((size_t)(b * 3136) + gy * 56 + gx) * 128 + h * 32;
#pragma unroll
        for (int n = 0; n < 2; ++n) {
            float val = (n == 0) ? o0[r] : o1[r];
            int d = 16 * n + cc;
            unsigned short hv = f2b(val);
            unsigned short lv = f2b(val - b2f(hv));
            attn_h[base + d] = hv;
            attn_l[base + d] = lv;
        }
    }
}

extern "C" void kernel_launch(void* const* d_in, const int* in_sizes, int n_in,
                              void* d_out, int out_size, void* d_ws, size_t ws_size,
                              hipStream_t stream)
{
    const float* x     = (const float*)d_in[0];
    const float* Wqkv  = (const float*)d_in[1];
    const float* bqkv  = (const float*)d_in[2];
    const float* rpb   = (const float*)d_in[3];
    const float* Wproj = (const float*)d_in[4];
    const float* bproj = (const float*)d_in[5];
    float* out = (float*)d_out;

    char* ws = (char*)d_ws;
    float*          qsb  = (float*)(ws + QS_OFF);
    unsigned short* kbuf = (unsigned short*)(ws + K_OFF);
    unsigned short* vbuf = (unsigned short*)(ws + V_OFF);
    unsigned short* xh   = (unsigned short*)(ws + XH_OFF);   // -> attn_h after natt
    unsigned short* xl   = (unsigned short*)(ws + XL_OFF);   // -> attn_l after natt
    unsigned short* wqh  = (unsigned short*)(ws + WQH_OFF);
    unsigned short* wql  = (unsigned short*)(ws + WQL_OFF);
    unsigned short* wph  = (unsigned short*)(ws + WPH_OFF);
    unsigned short* wpl  = (unsigned short*)(ws + WPL_OFF);

    // 0) split x, W_qkv, W_proj into (hi,lo) bf16
    split_k<<<3200, 256, 0, stream>>>(x, Wqkv, Wproj, xh, xl, wqh, wql, wph, wpl);

    // 1) QKV projection: 392 m-tiles x 6 n-tiles of 64
    gemm_mfma<1><<<dim3(392, 6), 256, 0, stream>>>(xh, xl, wqh, wql, bqkv,
                                                   qsb, kbuf, vbuf, nullptr);

    // 2) neighborhood attention (MFMA): 49 tiles x 4 heads x 8 batch
    natt_k<<<dim3(49, NH, 8), 256, 0, stream>>>(qsb, kbuf, vbuf, rpb, xh, xl);

    // 3) output projection: 392 x 2
    gemm_mfma<0><<<dim3(392, 2), 256, 0, stream>>>(xh, xl, wph, wpl, bproj,
                                                   nullptr, nullptr, nullptr, out);
}

// Round 6
// 72.506 us; speedup vs baseline: 1.4716x; 1.4716x over previous
//
#include <hip/hip_runtime.h>
#include <hip/hip_bf16.h>

#define NH 4
#define HD 32
#define PAD 3
#define HW 56
#define NPIX (8*HW*HW)          // 25088 pixels
#define SCALE 0.17677669529663687f

// ---------------- workspace layout (bytes) ----------------
// qs    : f32  [8][4][56][56][32]   12,845,056
// kbuf  : bf16 [8][4][56][56][32]    6,422,528
// vbuf  : bf16 [8][4][56][56][32]    6,422,528
// xh/xl : bf16 [25088][128]          6,422,528 each   (reused as attn_h/attn_l)
// W splits: qkv hi/lo 98,304 each; proj hi/lo 32,768 each
#define QS_OFF   0
#define K_OFF    12845056
#define V_OFF    (K_OFF + 6422528)
#define XH_OFF   (V_OFF + 6422528)      // = attn_h after natt
#define XL_OFF   (XH_OFF + 6422528)     // = attn_l after natt
#define WQH_OFF  (XL_OFF + 6422528)
#define WQL_OFF  (WQH_OFF + 98304)
#define WPH_OFF  (WQL_OFF + 98304)
#define WPL_OFF  (WPH_OFF + 32768)

typedef __attribute__((ext_vector_type(8))) short short8v;
typedef __attribute__((ext_vector_type(4))) float f32x4;

__device__ __forceinline__ float blo(unsigned u) { return __uint_as_float(u << 16); }
__device__ __forceinline__ float bhi(unsigned u) { return __uint_as_float(u & 0xffff0000u); }

__device__ __forceinline__ unsigned short f2b(float x) {       // f32 -> bf16 bits, RNE
    unsigned u = __float_as_uint(x);
    unsigned r = (u + 0x7fffu + ((u >> 16) & 1u)) >> 16;
    return (unsigned short)r;
}
__device__ __forceinline__ float b2f(unsigned short s) { return __uint_as_float((unsigned)s << 16); }

__device__ __forceinline__ float dot8(const float* q8, uint4 k) {
    float s;
    s  = q8[0] * blo(k.x); s = fmaf(q8[1], bhi(k.x), s);
    s  = fmaf(q8[2], blo(k.y), s); s = fmaf(q8[3], bhi(k.y), s);
    s  = fmaf(q8[4], blo(k.z), s); s = fmaf(q8[5], bhi(k.z), s);
    s  = fmaf(q8[6], blo(k.w), s); s = fmaf(q8[7], bhi(k.w), s);
    return s;
}
__device__ __forceinline__ void axpy8(float* a8, float e, uint4 v) {
    a8[0] = fmaf(e, blo(v.x), a8[0]); a8[1] = fmaf(e, bhi(v.x), a8[1]);
    a8[2] = fmaf(e, blo(v.y), a8[2]); a8[3] = fmaf(e, bhi(v.y), a8[3]);
    a8[4] = fmaf(e, blo(v.z), a8[4]); a8[5] = fmaf(e, bhi(v.z), a8[5]);
    a8[6] = fmaf(e, blo(v.w), a8[6]); a8[7] = fmaf(e, bhi(v.w), a8[7]);
}

// quad (4-lane) sum via DPP quad_perm: xor1 = 0xB1, xor2 = 0x4E. VALU-only.
__device__ __forceinline__ float quad_sum(float x) {
    x += __int_as_float(__builtin_amdgcn_update_dpp(0, __float_as_int(x), 0xB1, 0xF, 0xF, true));
    x += __int_as_float(__builtin_amdgcn_update_dpp(0, __float_as_int(x), 0x4E, 0xF, 0xF, true));
    return x;
}

// ---------------------------------------------------------------------------
// Pre-split: f32 -> (hi, lo) bf16 pairs for x, W_qkv, W_proj. One dispatch.
// ---------------------------------------------------------------------------
__global__ __launch_bounds__(256) void split_k(
    const float* __restrict__ x, const float* __restrict__ wq, const float* __restrict__ wp,
    unsigned short* __restrict__ xh, unsigned short* __restrict__ xl,
    unsigned short* __restrict__ wqh, unsigned short* __restrict__ wql,
    unsigned short* __restrict__ wph, unsigned short* __restrict__ wpl)
{
    int idx = blockIdx.x * 256 + threadIdx.x;
    if (idx >= 819200) return;
    const float* src; unsigned short *dh, *dl; int off;
    if (idx < 802816)      { src = x;  dh = xh;  dl = xl;  off = idx; }
    else if (idx < 815104) { src = wq; dh = wqh; dl = wql; off = idx - 802816; }
    else                   { src = wp; dh = wph; dl = wpl; off = idx - 815104; }
    float4 v = ((const float4*)src)[off];
    ushort4 h, l;
    h.x = f2b(v.x); l.x = f2b(v.x - b2f(h.x));
    h.y = f2b(v.y); l.y = f2b(v.y - b2f(h.y));
    h.z = f2b(v.z); l.z = f2b(v.z - b2f(h.z));
    h.w = f2b(v.w); l.w = f2b(v.w - b2f(h.w));
    ((ushort4*)dh)[off] = h;
    ((ushort4*)dl)[off] = l;
}

// ---------------------------------------------------------------------------
// MFMA GEMM (bf16x2 split): out[m][n] = sum_k A[m][k]*W[n][k] + bias[n]
// Staging now uses global_load_lds width=16 (async DMA, no VGPR round-trip).
// LDS dest is LINEAR; the XOR swizzle (byte ^= (row&7)<<4, an involution on
// byte-bit 4 only) is applied to the global SOURCE address instead, so the
// swizzled read side is unchanged (rule #21: inverse-swz source + swz read).
// BM=BN=64, K=128 whole in LDS (64 KB -> 2 blocks/CU). 4 waves (2x2), each
// 32x32 via 2x2 frags of 16x16x32 bf16, 3 MFMA per frag (AhBh+AhBl+AlBh).
// ---------------------------------------------------------------------------
template <int SELQKV>
__global__ __launch_bounds__(256, 2) void gemm_mfma(
    const unsigned short* __restrict__ Ah, const unsigned short* __restrict__ Al,
    const unsigned short* __restrict__ Bh, const unsigned short* __restrict__ Bl,
    const float* __restrict__ bias,
    float* __restrict__ outq, unsigned short* __restrict__ outk,
    unsigned short* __restrict__ outv, float* __restrict__ outp)
{
    __shared__ unsigned short sAh[64 * 128];
    __shared__ unsigned short sAl[64 * 128];
    __shared__ unsigned short sBh[64 * 128];
    __shared__ unsigned short sBl[64 * 128];

    const int tid = threadIdx.x;
    const int m0 = blockIdx.x * 64;
    const int n0 = blockIdx.y * 64;

    // ---- stage via global_load_lds (16B/lane), pre-swizzled source ----
    {
        const char* gAh = (const char*)(Ah + (size_t)m0 * 128);
        const char* gAl = (const char*)(Al + (size_t)m0 * 128);
        const char* gBh = (const char*)(Bh + (size_t)n0 * 128);
        const char* gBl = (const char*)(Bl + (size_t)n0 * 128);
#pragma unroll
        for (int it = 0; it < 4; ++it) {
            int p    = it * 4096 + tid * 16;            // linear LDS byte
            int row  = p >> 8;                          // 256 B per row
            size_t gb = (size_t)row * 256 + ((p & 0xF0) ^ ((row & 7) << 4)) + (p & 15);
            __builtin_amdgcn_global_load_lds(
                (const __attribute__((address_space(1))) unsigned int*)(gAh + gb),
                (__attribute__((address_space(3))) unsigned int*)((char*)sAh + p), 16, 0, 0);
            __builtin_amdgcn_global_load_lds(
                (const __attribute__((address_space(1))) unsigned int*)(gAl + gb),
                (__attribute__((address_space(3))) unsigned int*)((char*)sAl + p), 16, 0, 0);
            __builtin_amdgcn_global_load_lds(
                (const __attribute__((address_space(1))) unsigned int*)(gBh + gb),
                (__attribute__((address_space(3))) unsigned int*)((char*)sBh + p), 16, 0, 0);
            __builtin_amdgcn_global_load_lds(
                (const __attribute__((address_space(1))) unsigned int*)(gBl + gb),
                (__attribute__((address_space(3))) unsigned int*)((char*)sBl + p), 16, 0, 0);
        }
    }
    __syncthreads();

    const int lane = tid & 63;
    const int w  = tid >> 6;
    const int wr = w >> 1, wc = w & 1;       // 2x2 waves -> 64x64
    const int fr  = lane & 15;
    const int kqb = (lane >> 4) * 16;        // k byte offset within 64B group

    f32x4 acc[2][2];
#pragma unroll
    for (int i = 0; i < 2; ++i)
#pragma unroll
        for (int j = 0; j < 2; ++j) acc[i][j] = (f32x4){0.f, 0.f, 0.f, 0.f};

#pragma unroll
    for (int ks = 0; ks < 4; ++ks) {
        short8v ah[2], al[2], bh[2], bl[2];
#pragma unroll
        for (int mi = 0; mi < 2; ++mi) {
            int row = wr * 32 + mi * 16 + fr;
            int byte = (row * 256 + ks * 64 + kqb) ^ ((row & 7) << 4);
            ah[mi] = *(const short8v*)((const char*)sAh + byte);
            al[mi] = *(const short8v*)((const char*)sAl + byte);
        }
#pragma unroll
        for (int ni = 0; ni < 2; ++ni) {
            int row = wc * 32 + ni * 16 + fr;
            int byte = (row * 256 + ks * 64 + kqb) ^ ((row & 7) << 4);
            bh[ni] = *(const short8v*)((const char*)sBh + byte);
            bl[ni] = *(const short8v*)((const char*)sBl + byte);
        }
#pragma unroll
        for (int mi = 0; mi < 2; ++mi)
#pragma unroll
            for (int ni = 0; ni < 2; ++ni) {
                acc[mi][ni] = __builtin_amdgcn_mfma_f32_16x16x32_bf16(ah[mi], bh[ni], acc[mi][ni], 0, 0, 0);
                acc[mi][ni] = __builtin_amdgcn_mfma_f32_16x16x32_bf16(ah[mi], bl[ni], acc[mi][ni], 0, 0, 0);
                acc[mi][ni] = __builtin_amdgcn_mfma_f32_16x16x32_bf16(al[mi], bh[ni], acc[mi][ni], 0, 0, 0);
            }
    }

    const int cl = lane & 15;
    const int rq = lane >> 4;

#pragma unroll
    for (int mi = 0; mi < 2; ++mi) {
#pragma unroll
        for (int reg = 0; reg < 4; ++reg) {
            int m = m0 + wr * 32 + mi * 16 + rq * 4 + reg;
            if constexpr (SELQKV) {
                int b = m / 3136;
                int r = m - b * 3136;
                int y = r / 56;
                int x = r - y * 56;
#pragma unroll
                for (int ni = 0; ni < 2; ++ni) {
                    int nn = n0 + wc * 32 + ni * 16 + cl;   // 0..383
                    float val = acc[mi][ni][reg] + bias[nn];
                    int sel = nn >> 7;                      // 0=q 1=k 2=v
                    int nl = nn & 127;
                    int h = nl >> 5, d = nl & 31;
                    size_t oi = ((size_t)((b * NH + h) * 3136) + y * 56 + x) * 32 + d;
                    if (sel == 0)      outq[oi] = val * SCALE;
                    else if (sel == 1) outk[oi] = f2b(val);
                    else               outv[oi] = f2b(val);
                }
            } else {
#pragma unroll
                for (int ni = 0; ni < 2; ++ni) {
                    int nn = n0 + wc * 32 + ni * 16 + cl;
                    outp[(size_t)m * 128 + nn] = acc[mi][ni][reg] + bias[nn];
                }
            }
        }
    }
}

// ---------------------------------------------------------------------------
// Neighborhood attention (round-4 version, verbatim): 4 threads per
// (pixel, head), d-chunk split. Thread (p, c) owns dims [c*8, c*8+8).
// Block = 7x28 pixel tile, 784 active / 832 threads (13 waves).
// Grid = 8 y-tiles x 2 x-tiles x 4 heads x 8 batch = 512 blocks = 2.0/CU.
// Halo 13x34 k/v bf16 in LDS, layout [pix][c]. Partial scores quad-summed
// via DPP. Zero-filled OOB halo matches reference zero-padding.
// Output written directly as (hi,lo) bf16 for the proj GEMM.
// ---------------------------------------------------------------------------
__global__ __launch_bounds__(832) void natt_k(
    const float* __restrict__ qs, const unsigned short* __restrict__ kb,
    const unsigned short* __restrict__ vb, const float* __restrict__ rpb,
    unsigned short* __restrict__ attn_h, unsigned short* __restrict__ attn_l)
{
    __shared__ uint4 ks[442 * 4];   // [pix][c], pix = i*34+j, halo 13x34
    __shared__ uint4 vs[442 * 4];

    const int tid = threadIdx.x;
    const int b = blockIdx.z, h = blockIdx.y;
    const int yt = blockIdx.x >> 1, xt = blockIdx.x & 1;
    const int y0 = yt * 7, x0 = xt * 28;
    const int bh = b * NH + h;

    const uint4* kg = (const uint4*)kb;  // 4 uint4 per pixel (32 bf16)
    const uint4* vg = (const uint4*)vb;
    for (int idx = tid; idx < 1768; idx += 832) {   // 442 pix * 4 chunks
        int pix = idx >> 2, c = idx & 3;
        int i = pix / 34;
        int j = pix - i * 34;
        int y = y0 + i - PAD;
        int x = x0 + j - PAD;
        uint4 zk = make_uint4(0u, 0u, 0u, 0u);
        uint4 zv = make_uint4(0u, 0u, 0u, 0u);
        if ((unsigned)y < 56u && (unsigned)x < 56u) {
            int g = ((bh * 3136) + y * 56 + x) * 4 + c;
            zk = kg[g];
            zv = vg[g];
        }
        ks[idx] = zk;
        vs[idx] = zv;
    }
    __syncthreads();

    if (tid >= 784) return;
    const int p = tid >> 2, c = tid & 3;   // quads 4-aligned -> DPP partners co-active
    const int py = p / 28;
    const int pxx = p - py * 28;

    float q[8];
    {
        const float4* qgp = (const float4*)(qs +
            ((size_t)(bh * 3136) + (y0 + py) * 56 + (x0 + pxx)) * 32 + c * 8);
        float4 t0 = qgp[0], t1 = qgp[1];
        q[0] = t0.x; q[1] = t0.y; q[2] = t0.z; q[3] = t0.w;
        q[4] = t1.x; q[5] = t1.y; q[6] = t1.z; q[7] = t1.w;
    }

    float acc[8];
#pragma unroll
    for (int d = 0; d < 8; ++d) acc[d] = 0.f;
    float l = 0.f;

    const float* rph = rpb + h * 49;       // uniform index -> scalar loads

#pragma unroll
    for (int dy = 0; dy < 7; ++dy) {
        int rowbase = ((py + dy) * 34 + pxx) * 4 + c;
#pragma unroll
        for (int dx = 0; dx < 7; ++dx) {
            int pc = rowbase + dx * 4;
            float s  = dot8(q, ks[pc]);
            float sf = quad_sum(s) + rph[dy * 7 + dx];
            float e  = __expf(sf);
            l += e;
            axpy8(acc, e, vs[pc]);
        }
    }

    float rl = 1.0f / l;

    // pack 8 dims -> (hi, lo) bf16 uint4, single b128 store each
    unsigned short hv[8], lv[8];
#pragma unroll
    for (int d = 0; d < 8; ++d) {
        float val = acc[d] * rl;
        hv[d] = f2b(val);
        lv[d] = f2b(val - b2f(hv[d]));
    }
    uint4 uh, ul;
    uh.x = (unsigned)hv[0] | ((unsigned)hv[1] << 16);
    uh.y = (unsigned)hv[2] | ((unsigned)hv[3] << 16);
    uh.z = (unsigned)hv[4] | ((unsigned)hv[5] << 16);
    uh.w = (unsigned)hv[6] | ((unsigned)hv[7] << 16);
    ul.x = (unsigned)lv[0] | ((unsigned)lv[1] << 16);
    ul.y = (unsigned)lv[2] | ((unsigned)lv[3] << 16);
    ul.z = (unsigned)lv[4] | ((unsigned)lv[5] << 16);
    ul.w = (unsigned)lv[6] | ((unsigned)lv[7] << 16);

    size_t base = ((size_t)(b * 3136) + (y0 + py) * 56 + (x0 + pxx)) * 128 + h * 32 + c * 8;
    *(uint4*)(attn_h + base) = uh;
    *(uint4*)(attn_l + base) = ul;
}

extern "C" void kernel_launch(void* const* d_in, const int* in_sizes, int n_in,
                              void* d_out, int out_size, void* d_ws, size_t ws_size,
                              hipStream_t stream)
{
    const float* x     = (const float*)d_in[0];
    const float* Wqkv  = (const float*)d_in[1];
    const float* bqkv  = (const float*)d_in[2];
    const float* rpb   = (const float*)d_in[3];
    const float* Wproj = (const float*)d_in[4];
    const float* bproj = (const float*)d_in[5];
    float* out = (float*)d_out;

    char* ws = (char*)d_ws;
    float*          qsb  = (float*)(ws + QS_OFF);
    unsigned short* kbuf = (unsigned short*)(ws + K_OFF);
    unsigned short* vbuf = (unsigned short*)(ws + V_OFF);
    unsigned short* xh   = (unsigned short*)(ws + XH_OFF);   // -> attn_h after natt
    unsigned short* xl   = (unsigned short*)(ws + XL_OFF);   // -> attn_l after natt
    unsigned short* wqh  = (unsigned short*)(ws + WQH_OFF);
    unsigned short* wql  = (unsigned short*)(ws + WQL_OFF);
    unsigned short* wph  = (unsigned short*)(ws + WPH_OFF);
    unsigned short* wpl  = (unsigned short*)(ws + WPL_OFF);

    // 0) split x, W_qkv, W_proj into (hi,lo) bf16
    split_k<<<3200, 256, 0, stream>>>(x, Wqkv, Wproj, xh, xl, wqh, wql, wph, wpl);

    // 1) QKV projection: 392 m-tiles x 6 n-tiles of 64
    gemm_mfma<1><<<dim3(392, 6), 256, 0, stream>>>(xh, xl, wqh, wql, bqkv,
                                                   qsb, kbuf, vbuf, nullptr);

    // 2) neighborhood attention: 16 tiles x 4 heads x 8 batch, 832 thr/blk
    natt_k<<<dim3(16, NH, 8), 832, 0, stream>>>(qsb, kbuf, vbuf, rpb, xh, xl);

    // 3) output projection: 392 x 2
    gemm_mfma<0><<<dim3(392, 2), 256, 0, stream>>>(xh, xl, wph, wpl, bproj,
                                                   nullptr, nullptr, nullptr, out);
}

// Round 7
// 66.834 us; speedup vs baseline: 1.5965x; 1.0849x over previous
//
#include <hip/hip_runtime.h>
#include <hip/hip_bf16.h>

#define NH 4
#define HD 32
#define PAD 3
#define HW 56
#define NPIX (8*HW*HW)          // 25088 pixels
#define SCALE 0.17677669529663687f

// ---------------- workspace layout (bytes) ----------------
// qs    : f32  [8][4][56][56][32]   12,845,056
// kbuf  : bf16 [8][4][56][56][32]    6,422,528
// vbuf  : bf16 [8][4][56][56][32]    6,422,528
// xh/xl : bf16 [25088][128]          6,422,528 each   (attn_h/attn_l from natt)
// W splits: qkv hi/lo 98,304 each; proj hi/lo 32,768 each
#define QS_OFF   0
#define K_OFF    12845056
#define V_OFF    (K_OFF + 6422528)
#define XH_OFF   (V_OFF + 6422528)      // attn_h (written by natt)
#define XL_OFF   (XH_OFF + 6422528)     // attn_l
#define WQH_OFF  (XL_OFF + 6422528)
#define WQL_OFF  (WQH_OFF + 98304)
#define WPH_OFF  (WQL_OFF + 98304)
#define WPL_OFF  (WPH_OFF + 32768)

typedef __attribute__((ext_vector_type(8))) short short8v;
typedef __attribute__((ext_vector_type(4))) float f32x4;

__device__ __forceinline__ float blo(unsigned u) { return __uint_as_float(u << 16); }
__device__ __forceinline__ float bhi(unsigned u) { return __uint_as_float(u & 0xffff0000u); }

__device__ __forceinline__ unsigned short f2b(float x) {       // f32 -> bf16 bits, RNE
    unsigned u = __float_as_uint(x);
    unsigned r = (u + 0x7fffu + ((u >> 16) & 1u)) >> 16;
    return (unsigned short)r;
}
__device__ __forceinline__ float b2f(unsigned short s) { return __uint_as_float((unsigned)s << 16); }

__device__ __forceinline__ float dot8(const float* q8, uint4 k) {
    float s;
    s  = q8[0] * blo(k.x); s = fmaf(q8[1], bhi(k.x), s);
    s  = fmaf(q8[2], blo(k.y), s); s = fmaf(q8[3], bhi(k.y), s);
    s  = fmaf(q8[4], blo(k.z), s); s = fmaf(q8[5], bhi(k.z), s);
    s  = fmaf(q8[6], blo(k.w), s); s = fmaf(q8[7], bhi(k.w), s);
    return s;
}
__device__ __forceinline__ void axpy8(float* a8, float e, uint4 v) {
    a8[0] = fmaf(e, blo(v.x), a8[0]); a8[1] = fmaf(e, bhi(v.x), a8[1]);
    a8[2] = fmaf(e, blo(v.y), a8[2]); a8[3] = fmaf(e, bhi(v.y), a8[3]);
    a8[4] = fmaf(e, blo(v.z), a8[4]); a8[5] = fmaf(e, bhi(v.z), a8[5]);
    a8[6] = fmaf(e, blo(v.w), a8[6]); a8[7] = fmaf(e, bhi(v.w), a8[7]);
}

// quad (4-lane) sum via DPP quad_perm: xor1 = 0xB1, xor2 = 0x4E. VALU-only.
__device__ __forceinline__ float quad_sum(float x) {
    x += __int_as_float(__builtin_amdgcn_update_dpp(0, __float_as_int(x), 0xB1, 0xF, 0xF, true));
    x += __int_as_float(__builtin_amdgcn_update_dpp(0, __float_as_int(x), 0x4E, 0xF, 0xF, true));
    return x;
}

// ---------------------------------------------------------------------------
// Pre-split (weights only now): W_qkv 12288 f4 + W_proj 4096 f4 = 16384.
// ---------------------------------------------------------------------------
__global__ __launch_bounds__(256) void split_k(
    const float* __restrict__ wq, const float* __restrict__ wp,
    unsigned short* __restrict__ wqh, unsigned short* __restrict__ wql,
    unsigned short* __restrict__ wph, unsigned short* __restrict__ wpl)
{
    int idx = blockIdx.x * 256 + threadIdx.x;
    if (idx >= 16384) return;
    const float* src; unsigned short *dh, *dl; int off;
    if (idx < 12288) { src = wq; dh = wqh; dl = wql; off = idx; }
    else             { src = wp; dh = wph; dl = wpl; off = idx - 12288; }
    float4 v = ((const float4*)src)[off];
    ushort4 h, l;
    h.x = f2b(v.x); l.x = f2b(v.x - b2f(h.x));
    h.y = f2b(v.y); l.y = f2b(v.y - b2f(h.y));
    h.z = f2b(v.z); l.z = f2b(v.z - b2f(h.z));
    h.w = f2b(v.w); l.w = f2b(v.w - b2f(h.w));
    ((ushort4*)dh)[off] = h;
    ((ushort4*)dl)[off] = l;
}

// ---------------------------------------------------------------------------
// Fused-N MFMA GEMM (bf16x2 split): grid = 392 m-blocks, each block stages
// its 64x128 A-tile ONCE, then loops NPH n-phases restaging only the 32 KB
// B-tile (L2-resident weights). Minimizes A HBM traffic (was read NPH times).
//  SELQKV=1: NPH=6 (q/k/v scatter epilogue), A = f32 x, split in-kernel
//            (each x element split exactly once grid-wide).
//  SELQKV=0: NPH=2 (f32 row epilogue), A = attn hi/lo bf16 pairs.
// acc = Ah*Bh + Ah*Bl + Al*Bh per fragment, mfma_f32_16x16x32_bf16.
// LDS 64 KB (4 x 64x128 u16), XOR swizzle byte ^= (row&7)<<4.
// ---------------------------------------------------------------------------
template <int SELQKV>
__global__ __launch_bounds__(256, 2) void gemm_fused(
    const float* __restrict__ Af32,
    const unsigned short* __restrict__ Axh, const unsigned short* __restrict__ Axl,
    const unsigned short* __restrict__ Bgh, const unsigned short* __restrict__ Bgl,
    const float* __restrict__ bias,
    float* __restrict__ outq, unsigned short* __restrict__ outk,
    unsigned short* __restrict__ outv, float* __restrict__ outp)
{
    __shared__ unsigned short sAh[64 * 128];
    __shared__ unsigned short sAl[64 * 128];
    __shared__ unsigned short sBh[64 * 128];
    __shared__ unsigned short sBl[64 * 128];

    const int tid = threadIdx.x;
    const int m0 = blockIdx.x * 64;
    constexpr int NPH = SELQKV ? 6 : 2;

    // ---- stage A once ----
    if constexpr (SELQKV) {
        // f32 x -> hi/lo split (each element split once grid-wide)
#pragma unroll
        for (int it = 0; it < 8; ++it) {
            int idx = tid + it * 256;          // 0..2047 float4 chunks
            int row = idx >> 5;                // 0..63
            int c4  = idx & 31;
            float4 a = *(const float4*)(Af32 + (size_t)(m0 + row) * 128 + c4 * 4);
            int byte = (row * 256 + c4 * 8) ^ ((row & 7) << 4);
            ushort4 h, l;
            h.x = f2b(a.x); l.x = f2b(a.x - b2f(h.x));
            h.y = f2b(a.y); l.y = f2b(a.y - b2f(h.y));
            h.z = f2b(a.z); l.z = f2b(a.z - b2f(h.z));
            h.w = f2b(a.w); l.w = f2b(a.w - b2f(h.w));
            *(ushort4*)((char*)sAh + byte) = h;
            *(ushort4*)((char*)sAl + byte) = l;
        }
    } else {
        // pre-split bf16 pairs
#pragma unroll
        for (int it = 0; it < 4; ++it) {
            int chunk = it * 256 + tid;        // 0..1023
            int row = chunk >> 4, c16 = chunk & 15;
            int byte = (row * 256 + c16 * 16) ^ ((row & 7) << 4);
            size_t ga = (size_t)(m0 + row) * 128 + c16 * 8;
            *(uint4*)((char*)sAh + byte) = *(const uint4*)(Axh + ga);
            *(uint4*)((char*)sAl + byte) = *(const uint4*)(Axl + ga);
        }
    }

    const int lane = tid & 63;
    const int w  = tid >> 6;
    const int wr = w >> 1, wc = w & 1;       // 2x2 waves -> 64x64
    const int fr  = lane & 15;
    const int kqb = (lane >> 4) * 16;        // k byte offset within 64B group
    const int cl = lane & 15;
    const int rq = lane >> 4;

    for (int ph = 0; ph < NPH; ++ph) {
        const int n0 = ph * 64;
        if (ph > 0) __syncthreads();         // prior mfma reads done before B overwrite
        // ---- stage B tile (L2-resident weights / small) ----
#pragma unroll
        for (int it = 0; it < 4; ++it) {
            int chunk = it * 256 + tid;      // 0..1023
            int row = chunk >> 4, c16 = chunk & 15;
            int byte = (row * 256 + c16 * 16) ^ ((row & 7) << 4);
            size_t gb = (size_t)(n0 + row) * 128 + c16 * 8;
            *(uint4*)((char*)sBh + byte) = *(const uint4*)(Bgh + gb);
            *(uint4*)((char*)sBl + byte) = *(const uint4*)(Bgl + gb);
        }
        __syncthreads();

        f32x4 acc[2][2];
#pragma unroll
        for (int i = 0; i < 2; ++i)
#pragma unroll
            for (int j = 0; j < 2; ++j) acc[i][j] = (f32x4){0.f, 0.f, 0.f, 0.f};

#pragma unroll
        for (int ks = 0; ks < 4; ++ks) {
            short8v ah[2], al[2], bh[2], bl[2];
#pragma unroll
            for (int mi = 0; mi < 2; ++mi) {
                int row = wr * 32 + mi * 16 + fr;
                int byte = (row * 256 + ks * 64 + kqb) ^ ((row & 7) << 4);
                ah[mi] = *(const short8v*)((const char*)sAh + byte);
                al[mi] = *(const short8v*)((const char*)sAl + byte);
            }
#pragma unroll
            for (int ni = 0; ni < 2; ++ni) {
                int row = wc * 32 + ni * 16 + fr;
                int byte = (row * 256 + ks * 64 + kqb) ^ ((row & 7) << 4);
                bh[ni] = *(const short8v*)((const char*)sBh + byte);
                bl[ni] = *(const short8v*)((const char*)sBl + byte);
            }
#pragma unroll
            for (int mi = 0; mi < 2; ++mi)
#pragma unroll
                for (int ni = 0; ni < 2; ++ni) {
                    acc[mi][ni] = __builtin_amdgcn_mfma_f32_16x16x32_bf16(ah[mi], bh[ni], acc[mi][ni], 0, 0, 0);
                    acc[mi][ni] = __builtin_amdgcn_mfma_f32_16x16x32_bf16(ah[mi], bl[ni], acc[mi][ni], 0, 0, 0);
                    acc[mi][ni] = __builtin_amdgcn_mfma_f32_16x16x32_bf16(al[mi], bh[ni], acc[mi][ni], 0, 0, 0);
                }
        }

        // ---- epilogue: C/D layout col=lane&15, row=4*(lane>>4)+reg ----
#pragma unroll
        for (int mi = 0; mi < 2; ++mi) {
#pragma unroll
            for (int reg = 0; reg < 4; ++reg) {
                int m = m0 + wr * 32 + mi * 16 + rq * 4 + reg;
                if constexpr (SELQKV) {
                    int b = m / 3136;
                    int r = m - b * 3136;
                    int y = r / 56;
                    int x = r - y * 56;
#pragma unroll
                    for (int ni = 0; ni < 2; ++ni) {
                        int nn = n0 + wc * 32 + ni * 16 + cl;   // 0..383
                        float val = acc[mi][ni][reg] + bias[nn];
                        int sel = nn >> 7;                      // 0=q 1=k 2=v
                        int nl = nn & 127;
                        int h = nl >> 5, d = nl & 31;
                        size_t oi = ((size_t)((b * NH + h) * 3136) + y * 56 + x) * 32 + d;
                        if (sel == 0)      outq[oi] = val * SCALE;
                        else if (sel == 1) outk[oi] = f2b(val);
                        else               outv[oi] = f2b(val);
                    }
                } else {
#pragma unroll
                    for (int ni = 0; ni < 2; ++ni) {
                        int nn = n0 + wc * 32 + ni * 16 + cl;
                        outp[(size_t)m * 128 + nn] = acc[mi][ni][reg] + bias[nn];
                    }
                }
            }
        }
    }
}

// ---------------------------------------------------------------------------
// Neighborhood attention (round-4/6 version, verbatim): 4 threads per
// (pixel, head), d-chunk split. Thread (p, c) owns dims [c*8, c*8+8).
// Block = 7x28 pixel tile, 784 active / 832 threads (13 waves).
// Grid = 8 y-tiles x 2 x-tiles x 4 heads x 8 batch = 512 blocks = 2.0/CU.
// Halo 13x34 k/v bf16 in LDS, layout [pix][c]. Partial scores quad-summed
// via DPP. Zero-filled OOB halo matches reference zero-padding.
// Output written directly as (hi,lo) bf16 for the proj GEMM.
// ---------------------------------------------------------------------------
__global__ __launch_bounds__(832) void natt_k(
    const float* __restrict__ qs, const unsigned short* __restrict__ kb,
    const unsigned short* __restrict__ vb, const float* __restrict__ rpb,
    unsigned short* __restrict__ attn_h, unsigned short* __restrict__ attn_l)
{
    __shared__ uint4 ks[442 * 4];   // [pix][c], pix = i*34+j, halo 13x34
    __shared__ uint4 vs[442 * 4];

    const int tid = threadIdx.x;
    const int b = blockIdx.z, h = blockIdx.y;
    const int yt = blockIdx.x >> 1, xt = blockIdx.x & 1;
    const int y0 = yt * 7, x0 = xt * 28;
    const int bh = b * NH + h;

    const uint4* kg = (const uint4*)kb;  // 4 uint4 per pixel (32 bf16)
    const uint4* vg = (const uint4*)vb;
    for (int idx = tid; idx < 1768; idx += 832) {   // 442 pix * 4 chunks
        int pix = idx >> 2, c = idx & 3;
        int i = pix / 34;
        int j = pix - i * 34;
        int y = y0 + i - PAD;
        int x = x0 + j - PAD;
        uint4 zk = make_uint4(0u, 0u, 0u, 0u);
        uint4 zv = make_uint4(0u, 0u, 0u, 0u);
        if ((unsigned)y < 56u && (unsigned)x < 56u) {
            int g = ((bh * 3136) + y * 56 + x) * 4 + c;
            zk = kg[g];
            zv = vg[g];
        }
        ks[idx] = zk;
        vs[idx] = zv;
    }
    __syncthreads();

    if (tid >= 784) return;
    const int p = tid >> 2, c = tid & 3;   // quads 4-aligned -> DPP partners co-active
    const int py = p / 28;
    const int pxx = p - py * 28;

    float q[8];
    {
        const float4* qgp = (const float4*)(qs +
            ((size_t)(bh * 3136) + (y0 + py) * 56 + (x0 + pxx)) * 32 + c * 8);
        float4 t0 = qgp[0], t1 = qgp[1];
        q[0] = t0.x; q[1] = t0.y; q[2] = t0.z; q[3] = t0.w;
        q[4] = t1.x; q[5] = t1.y; q[6] = t1.z; q[7] = t1.w;
    }

    float acc[8];
#pragma unroll
    for (int d = 0; d < 8; ++d) acc[d] = 0.f;
    float l = 0.f;

    const float* rph = rpb + h * 49;       // uniform index -> scalar loads

#pragma unroll
    for (int dy = 0; dy < 7; ++dy) {
        int rowbase = ((py + dy) * 34 + pxx) * 4 + c;
#pragma unroll
        for (int dx = 0; dx < 7; ++dx) {
            int pc = rowbase + dx * 4;
            float s  = dot8(q, ks[pc]);
            float sf = quad_sum(s) + rph[dy * 7 + dx];
            float e  = __expf(sf);
            l += e;
            axpy8(acc, e, vs[pc]);
        }
    }

    float rl = 1.0f / l;

    // pack 8 dims -> (hi, lo) bf16 uint4, single b128 store each
    unsigned short hv[8], lv[8];
#pragma unroll
    for (int d = 0; d < 8; ++d) {
        float val = acc[d] * rl;
        hv[d] = f2b(val);
        lv[d] = f2b(val - b2f(hv[d]));
    }
    uint4 uh, ul;
    uh.x = (unsigned)hv[0] | ((unsigned)hv[1] << 16);
    uh.y = (unsigned)hv[2] | ((unsigned)hv[3] << 16);
    uh.z = (unsigned)hv[4] | ((unsigned)hv[5] << 16);
    uh.w = (unsigned)hv[6] | ((unsigned)hv[7] << 16);
    ul.x = (unsigned)lv[0] | ((unsigned)lv[1] << 16);
    ul.y = (unsigned)lv[2] | ((unsigned)lv[3] << 16);
    ul.z = (unsigned)lv[4] | ((unsigned)lv[5] << 16);
    ul.w = (unsigned)lv[6] | ((unsigned)lv[7] << 16);

    size_t base = ((size_t)(b * 3136) + (y0 + py) * 56 + (x0 + pxx)) * 128 + h * 32 + c * 8;
    *(uint4*)(attn_h + base) = uh;
    *(uint4*)(attn_l + base) = ul;
}

extern "C" void kernel_launch(void* const* d_in, const int* in_sizes, int n_in,
                              void* d_out, int out_size, void* d_ws, size_t ws_size,
                              hipStream_t stream)
{
    const float* x     = (const float*)d_in[0];
    const float* Wqkv  = (const float*)d_in[1];
    const float* bqkv  = (const float*)d_in[2];
    const float* rpb   = (const float*)d_in[3];
    const float* Wproj = (const float*)d_in[4];
    const float* bproj = (const float*)d_in[5];
    float* out = (float*)d_out;

    char* ws = (char*)d_ws;
    float*          qsb  = (float*)(ws + QS_OFF);
    unsigned short* kbuf = (unsigned short*)(ws + K_OFF);
    unsigned short* vbuf = (unsigned short*)(ws + V_OFF);
    unsigned short* xh   = (unsigned short*)(ws + XH_OFF);   // attn_h (from natt)
    unsigned short* xl   = (unsigned short*)(ws + XL_OFF);   // attn_l
    unsigned short* wqh  = (unsigned short*)(ws + WQH_OFF);
    unsigned short* wql  = (unsigned short*)(ws + WQL_OFF);
    unsigned short* wph  = (unsigned short*)(ws + WPH_OFF);
    unsigned short* wpl  = (unsigned short*)(ws + WPL_OFF);

    // 0) split weights into (hi,lo) bf16 (tiny)
    split_k<<<64, 256, 0, stream>>>(Wqkv, Wproj, wqh, wql, wph, wpl);

    // 1) QKV projection: 392 m-blocks, 6 internal n-phases (A staged once)
    gemm_fused<1><<<392, 256, 0, stream>>>(x, nullptr, nullptr, wqh, wql, bqkv,
                                           qsb, kbuf, vbuf, nullptr);

    // 2) neighborhood attention: 16 tiles x 4 heads x 8 batch, 832 thr/blk
    natt_k<<<dim3(16, NH, 8), 832, 0, stream>>>(qsb, kbuf, vbuf, rpb, xh, xl);

    // 3) output projection: 392 m-blocks, 2 internal n-phases
    gemm_fused<0><<<392, 256, 0, stream>>>(nullptr, xh, xl, wph, wpl, bproj,
                                           nullptr, nullptr, nullptr, out);
}

// Round 8
// 61.236 us; speedup vs baseline: 1.7425x; 1.0914x over previous
//
#include <hip/hip_runtime.h>
#include <hip/hip_bf16.h>

#define NH 4
#define HD 32
#define PAD 3
#define HW 56
#define NPIX (8*HW*HW)          // 25088 pixels
#define SCALE 0.17677669529663687f

// ---------------- workspace layout (bytes) ----------------
// qs    : f32  [8][4][56][56][32]   12,845,056
// kbuf  : bf16 [8][4][56][56][32]    6,422,528
// vbuf  : bf16 [8][4][56][56][32]    6,422,528
// xh/xl : bf16 [25088][128]          6,422,528 each   (attn_h/attn_l from natt)
// W splits: qkv hi/lo 98,304 each; proj hi/lo 32,768 each
#define QS_OFF   0
#define K_OFF    12845056
#define V_OFF    (K_OFF + 6422528)
#define XH_OFF   (V_OFF + 6422528)      // attn_h (written by natt)
#define XL_OFF   (XH_OFF + 6422528)     // attn_l
#define WQH_OFF  (XL_OFF + 6422528)
#define WQL_OFF  (WQH_OFF + 98304)
#define WPH_OFF  (WQL_OFF + 98304)
#define WPL_OFF  (WPH_OFF + 32768)

typedef __attribute__((ext_vector_type(8))) short short8v;
typedef __attribute__((ext_vector_type(4))) float f32x4;

__device__ __forceinline__ float blo(unsigned u) { return __uint_as_float(u << 16); }
__device__ __forceinline__ float bhi(unsigned u) { return __uint_as_float(u & 0xffff0000u); }

__device__ __forceinline__ unsigned short f2b(float x) {       // f32 -> bf16 bits, RNE
    unsigned u = __float_as_uint(x);
    unsigned r = (u + 0x7fffu + ((u >> 16) & 1u)) >> 16;
    return (unsigned short)r;
}
__device__ __forceinline__ float b2f(unsigned short s) { return __uint_as_float((unsigned)s << 16); }

__device__ __forceinline__ float dot8(const float* q8, uint4 k) {
    float s;
    s  = q8[0] * blo(k.x); s = fmaf(q8[1], bhi(k.x), s);
    s  = fmaf(q8[2], blo(k.y), s); s = fmaf(q8[3], bhi(k.y), s);
    s  = fmaf(q8[4], blo(k.z), s); s = fmaf(q8[5], bhi(k.z), s);
    s  = fmaf(q8[6], blo(k.w), s); s = fmaf(q8[7], bhi(k.w), s);
    return s;
}
__device__ __forceinline__ void axpy8(float* a8, float e, uint4 v) {
    a8[0] = fmaf(e, blo(v.x), a8[0]); a8[1] = fmaf(e, bhi(v.x), a8[1]);
    a8[2] = fmaf(e, blo(v.y), a8[2]); a8[3] = fmaf(e, bhi(v.y), a8[3]);
    a8[4] = fmaf(e, blo(v.z), a8[4]); a8[5] = fmaf(e, bhi(v.z), a8[5]);
    a8[6] = fmaf(e, blo(v.w), a8[6]); a8[7] = fmaf(e, bhi(v.w), a8[7]);
}

// quad (4-lane) sum via DPP quad_perm: xor1 = 0xB1, xor2 = 0x4E. VALU-only.
__device__ __forceinline__ float quad_sum(float x) {
    x += __int_as_float(__builtin_amdgcn_update_dpp(0, __float_as_int(x), 0xB1, 0xF, 0xF, true));
    x += __int_as_float(__builtin_amdgcn_update_dpp(0, __float_as_int(x), 0x4E, 0xF, 0xF, true));
    return x;
}

// ---------------------------------------------------------------------------
// Pre-split (weights only): W_qkv 12288 f4 + W_proj 4096 f4 = 16384.
// ---------------------------------------------------------------------------
__global__ __launch_bounds__(256) void split_k(
    const float* __restrict__ wq, const float* __restrict__ wp,
    unsigned short* __restrict__ wqh, unsigned short* __restrict__ wql,
    unsigned short* __restrict__ wph, unsigned short* __restrict__ wpl)
{
    int idx = blockIdx.x * 256 + threadIdx.x;
    if (idx >= 16384) return;
    const float* src; unsigned short *dh, *dl; int off;
    if (idx < 12288) { src = wq; dh = wqh; dl = wql; off = idx; }
    else             { src = wp; dh = wph; dl = wpl; off = idx - 12288; }
    float4 v = ((const float4*)src)[off];
    ushort4 h, l;
    h.x = f2b(v.x); l.x = f2b(v.x - b2f(h.x));
    h.y = f2b(v.y); l.y = f2b(v.y - b2f(h.y));
    h.z = f2b(v.z); l.z = f2b(v.z - b2f(h.z));
    h.w = f2b(v.w); l.w = f2b(v.w - b2f(h.w));
    ((ushort4*)dh)[off] = h;
    ((ushort4*)dl)[off] = l;
}

// ---------------------------------------------------------------------------
// Fused-N MFMA GEMM (bf16x2 split), unchanged from round 7.
// grid = 392 m-blocks; A-tile staged once; NPH n-phases restage 32 KB B-tile.
//  SELQKV=1: NPH=6 (q/k/v scatter epilogue), A = f32 x split in-kernel.
//  SELQKV=0: NPH=2 (f32 rows), A = attn hi/lo bf16.
// ---------------------------------------------------------------------------
template <int SELQKV>
__global__ __launch_bounds__(256, 2) void gemm_fused(
    const float* __restrict__ Af32,
    const unsigned short* __restrict__ Axh, const unsigned short* __restrict__ Axl,
    const unsigned short* __restrict__ Bgh, const unsigned short* __restrict__ Bgl,
    const float* __restrict__ bias,
    float* __restrict__ outq, unsigned short* __restrict__ outk,
    unsigned short* __restrict__ outv, float* __restrict__ outp)
{
    __shared__ unsigned short sAh[64 * 128];
    __shared__ unsigned short sAl[64 * 128];
    __shared__ unsigned short sBh[64 * 128];
    __shared__ unsigned short sBl[64 * 128];

    const int tid = threadIdx.x;
    const int m0 = blockIdx.x * 64;
    constexpr int NPH = SELQKV ? 6 : 2;

    // ---- stage A once ----
    if constexpr (SELQKV) {
#pragma unroll
        for (int it = 0; it < 8; ++it) {
            int idx = tid + it * 256;          // 0..2047 float4 chunks
            int row = idx >> 5;                // 0..63
            int c4  = idx & 31;
            float4 a = *(const float4*)(Af32 + (size_t)(m0 + row) * 128 + c4 * 4);
            int byte = (row * 256 + c4 * 8) ^ ((row & 7) << 4);
            ushort4 h, l;
            h.x = f2b(a.x); l.x = f2b(a.x - b2f(h.x));
            h.y = f2b(a.y); l.y = f2b(a.y - b2f(h.y));
            h.z = f2b(a.z); l.z = f2b(a.z - b2f(h.z));
            h.w = f2b(a.w); l.w = f2b(a.w - b2f(h.w));
            *(ushort4*)((char*)sAh + byte) = h;
            *(ushort4*)((char*)sAl + byte) = l;
        }
    } else {
#pragma unroll
        for (int it = 0; it < 4; ++it) {
            int chunk = it * 256 + tid;        // 0..1023
            int row = chunk >> 4, c16 = chunk & 15;
            int byte = (row * 256 + c16 * 16) ^ ((row & 7) << 4);
            size_t ga = (size_t)(m0 + row) * 128 + c16 * 8;
            *(uint4*)((char*)sAh + byte) = *(const uint4*)(Axh + ga);
            *(uint4*)((char*)sAl + byte) = *(const uint4*)(Axl + ga);
        }
    }

    const int lane = tid & 63;
    const int w  = tid >> 6;
    const int wr = w >> 1, wc = w & 1;       // 2x2 waves -> 64x64
    const int fr  = lane & 15;
    const int kqb = (lane >> 4) * 16;        // k byte offset within 64B group
    const int cl = lane & 15;
    const int rq = lane >> 4;

    for (int ph = 0; ph < NPH; ++ph) {
        const int n0 = ph * 64;
        if (ph > 0) __syncthreads();         // prior mfma reads done before B overwrite
#pragma unroll
        for (int it = 0; it < 4; ++it) {
            int chunk = it * 256 + tid;      // 0..1023
            int row = chunk >> 4, c16 = chunk & 15;
            int byte = (row * 256 + c16 * 16) ^ ((row & 7) << 4);
            size_t gb = (size_t)(n0 + row) * 128 + c16 * 8;
            *(uint4*)((char*)sBh + byte) = *(const uint4*)(Bgh + gb);
            *(uint4*)((char*)sBl + byte) = *(const uint4*)(Bgl + gb);
        }
        __syncthreads();

        f32x4 acc[2][2];
#pragma unroll
        for (int i = 0; i < 2; ++i)
#pragma unroll
            for (int j = 0; j < 2; ++j) acc[i][j] = (f32x4){0.f, 0.f, 0.f, 0.f};

#pragma unroll
        for (int ks = 0; ks < 4; ++ks) {
            short8v ah[2], al[2], bh[2], bl[2];
#pragma unroll
            for (int mi = 0; mi < 2; ++mi) {
                int row = wr * 32 + mi * 16 + fr;
                int byte = (row * 256 + ks * 64 + kqb) ^ ((row & 7) << 4);
                ah[mi] = *(const short8v*)((const char*)sAh + byte);
                al[mi] = *(const short8v*)((const char*)sAl + byte);
            }
#pragma unroll
            for (int ni = 0; ni < 2; ++ni) {
                int row = wc * 32 + ni * 16 + fr;
                int byte = (row * 256 + ks * 64 + kqb) ^ ((row & 7) << 4);
                bh[ni] = *(const short8v*)((const char*)sBh + byte);
                bl[ni] = *(const short8v*)((const char*)sBl + byte);
            }
#pragma unroll
            for (int mi = 0; mi < 2; ++mi)
#pragma unroll
                for (int ni = 0; ni < 2; ++ni) {
                    acc[mi][ni] = __builtin_amdgcn_mfma_f32_16x16x32_bf16(ah[mi], bh[ni], acc[mi][ni], 0, 0, 0);
                    acc[mi][ni] = __builtin_amdgcn_mfma_f32_16x16x32_bf16(ah[mi], bl[ni], acc[mi][ni], 0, 0, 0);
                    acc[mi][ni] = __builtin_amdgcn_mfma_f32_16x16x32_bf16(al[mi], bh[ni], acc[mi][ni], 0, 0, 0);
                }
        }

        // ---- epilogue: C/D layout col=lane&15, row=4*(lane>>4)+reg ----
#pragma unroll
        for (int mi = 0; mi < 2; ++mi) {
#pragma unroll
            for (int reg = 0; reg < 4; ++reg) {
                int m = m0 + wr * 32 + mi * 16 + rq * 4 + reg;
                if constexpr (SELQKV) {
                    int b = m / 3136;
                    int r = m - b * 3136;
                    int y = r / 56;
                    int x = r - y * 56;
#pragma unroll
                    for (int ni = 0; ni < 2; ++ni) {
                        int nn = n0 + wc * 32 + ni * 16 + cl;   // 0..383
                        float val = acc[mi][ni][reg] + bias[nn];
                        int sel = nn >> 7;                      // 0=q 1=k 2=v
                        int nl = nn & 127;
                        int h = nl >> 5, d = nl & 31;
                        size_t oi = ((size_t)((b * NH + h) * 3136) + y * 56 + x) * 32 + d;
                        if (sel == 0)      outq[oi] = val * SCALE;
                        else if (sel == 1) outk[oi] = f2b(val);
                        else               outv[oi] = f2b(val);
                    }
                } else {
#pragma unroll
                    for (int ni = 0; ni < 2; ++ni) {
                        int nn = n0 + wc * 32 + ni * 16 + cl;
                        outp[(size_t)m * 128 + nn] = acc[mi][ni][reg] + bias[nn];
                    }
                }
            }
        }
    }
}

// ---------------------------------------------------------------------------
// Neighborhood attention v5: same per-thread algorithm as round 4/6/7
// (4 threads per (pixel,head), d-chunk split, DPP quad-sum), but block
// geometry changed for occupancy: 256 threads (4 waves), 8x8 pixel tile,
// halo 14x14 = 196 pixels -> LDS 24.5 KB.
//   occupancy limits: waves 8 blk/CU, LDS 6 blk/CU, VGPR(<=85) 6 blk/CU
//   -> ~6 blocks = 24 waves/CU (was 13 waves: 832-thr block + ~85 VGPR
//      excluded a 2nd resident block).  Grid 1568 = 6.1/CU.
// __launch_bounds__(256,4): >=4 waves/SIMD guaranteed, VGPR cap 128 (no
// spill risk - round 3 lesson).  Numerics bitwise-identical to round 7.
// ---------------------------------------------------------------------------
__global__ __launch_bounds__(256, 4) void natt_k(
    const float* __restrict__ qs, const unsigned short* __restrict__ kb,
    const unsigned short* __restrict__ vb, const float* __restrict__ rpb,
    unsigned short* __restrict__ attn_h, unsigned short* __restrict__ attn_l)
{
    __shared__ uint4 ks[196 * 4];   // [pix][c], pix = i*14+j, halo 14x14
    __shared__ uint4 vs[196 * 4];

    const int tid = threadIdx.x;
    const int b = blockIdx.z, h = blockIdx.y;
    const int tyy = blockIdx.x / 7, txx = blockIdx.x - tyy * 7;  // 7x7 tiles
    const int y0 = tyy * 8, x0 = txx * 8;
    const int bh = b * NH + h;

    const uint4* kg = (const uint4*)kb;  // 4 uint4 per pixel (32 bf16)
    const uint4* vg = (const uint4*)vb;
    for (int idx = tid; idx < 784; idx += 256) {   // 196 pix * 4 chunks
        int pix = idx >> 2, c = idx & 3;
        int i = pix / 14;
        int j = pix - i * 14;
        int y = y0 + i - PAD;
        int x = x0 + j - PAD;
        uint4 zk = make_uint4(0u, 0u, 0u, 0u);
        uint4 zv = make_uint4(0u, 0u, 0u, 0u);
        if ((unsigned)y < 56u && (unsigned)x < 56u) {
            int g = ((bh * 3136) + y * 56 + x) * 4 + c;
            zk = kg[g];
            zv = vg[g];
        }
        ks[idx] = zk;
        vs[idx] = zv;
    }
    __syncthreads();

    const int p = tid >> 2, c = tid & 3;   // quads 4-aligned -> DPP partners co-active
    const int py = p >> 3;
    const int pxx = p & 7;

    float q[8];
    {
        const float4* qgp = (const float4*)(qs +
            ((size_t)(bh * 3136) + (y0 + py) * 56 + (x0 + pxx)) * 32 + c * 8);
        float4 t0 = qgp[0], t1 = qgp[1];
        q[0] = t0.x; q[1] = t0.y; q[2] = t0.z; q[3] = t0.w;
        q[4] = t1.x; q[5] = t1.y; q[6] = t1.z; q[7] = t1.w;
    }

    float acc[8];
#pragma unroll
    for (int d = 0; d < 8; ++d) acc[d] = 0.f;
    float l = 0.f;

    const float* rph = rpb + h * 49;       // uniform index -> scalar loads

#pragma unroll
    for (int dy = 0; dy < 7; ++dy) {
        int rowbase = ((py + dy) * 14 + pxx) * 4 + c;
#pragma unroll
        for (int dx = 0; dx < 7; ++dx) {
            int pc = rowbase + dx * 4;
            float s  = dot8(q, ks[pc]);
            float sf = quad_sum(s) + rph[dy * 7 + dx];
            float e  = __expf(sf);
            l += e;
            axpy8(acc, e, vs[pc]);
        }
    }

    float rl = 1.0f / l;

    // pack 8 dims -> (hi, lo) bf16 uint4, single b128 store each
    unsigned short hv[8], lv[8];
#pragma unroll
    for (int d = 0; d < 8; ++d) {
        float val = acc[d] * rl;
        hv[d] = f2b(val);
        lv[d] = f2b(val - b2f(hv[d]));
    }
    uint4 uh, ul;
    uh.x = (unsigned)hv[0] | ((unsigned)hv[1] << 16);
    uh.y = (unsigned)hv[2] | ((unsigned)hv[3] << 16);
    uh.z = (unsigned)hv[4] | ((unsigned)hv[5] << 16);
    uh.w = (unsigned)hv[6] | ((unsigned)hv[7] << 16);
    ul.x = (unsigned)lv[0] | ((unsigned)lv[1] << 16);
    ul.y = (unsigned)lv[2] | ((unsigned)lv[3] << 16);
    ul.z = (unsigned)lv[4] | ((unsigned)lv[5] << 16);
    ul.w = (unsigned)lv[6] | ((unsigned)lv[7] << 16);

    size_t base = ((size_t)(b * 3136) + (y0 + py) * 56 + (x0 + pxx)) * 128 + h * 32 + c * 8;
    *(uint4*)(attn_h + base) = uh;
    *(uint4*)(attn_l + base) = ul;
}

extern "C" void kernel_launch(void* const* d_in, const int* in_sizes, int n_in,
                              void* d_out, int out_size, void* d_ws, size_t ws_size,
                              hipStream_t stream)
{
    const float* x     = (const float*)d_in[0];
    const float* Wqkv  = (const float*)d_in[1];
    const float* bqkv  = (const float*)d_in[2];
    const float* rpb   = (const float*)d_in[3];
    const float* Wproj = (const float*)d_in[4];
    const float* bproj = (const float*)d_in[5];
    float* out = (float*)d_out;

    char* ws = (char*)d_ws;
    float*          qsb  = (float*)(ws + QS_OFF);
    unsigned short* kbuf = (unsigned short*)(ws + K_OFF);
    unsigned short* vbuf = (unsigned short*)(ws + V_OFF);
    unsigned short* xh   = (unsigned short*)(ws + XH_OFF);   // attn_h (from natt)
    unsigned short* xl   = (unsigned short*)(ws + XL_OFF);   // attn_l
    unsigned short* wqh  = (unsigned short*)(ws + WQH_OFF);
    unsigned short* wql  = (unsigned short*)(ws + WQL_OFF);
    unsigned short* wph  = (unsigned short*)(ws + WPH_OFF);
    unsigned short* wpl  = (unsigned short*)(ws + WPL_OFF);

    // 0) split weights into (hi,lo) bf16 (tiny)
    split_k<<<64, 256, 0, stream>>>(Wqkv, Wproj, wqh, wql, wph, wpl);

    // 1) QKV projection: 392 m-blocks, 6 internal n-phases (A staged once)
    gemm_fused<1><<<392, 256, 0, stream>>>(x, nullptr, nullptr, wqh, wql, bqkv,
                                           qsb, kbuf, vbuf, nullptr);

    // 2) neighborhood attention: 49 tiles x 4 heads x 8 batch, 256 thr/blk
    natt_k<<<dim3(49, NH, 8), 256, 0, stream>>>(qsb, kbuf, vbuf, rpb, xh, xl);

    // 3) output projection: 392 m-blocks, 2 internal n-phases
    gemm_fused<0><<<392, 256, 0, stream>>>(nullptr, xh, xl, wph, wpl, bproj,
                                           nullptr, nullptr, nullptr, out);
}

// Round 9
// 60.493 us; speedup vs baseline: 1.7639x; 1.0123x over previous
//
#include <hip/hip_runtime.h>
#include <hip/hip_bf16.h>

#define NH 4
#define HD 32
#define PAD 3
#define HW 56
#define NPIX (8*HW*HW)          // 25088 pixels
#define SCALE 0.17677669529663687f

// ---------------- workspace layout (bytes) ----------------
// qs    : f32  [8][4][56][56][32]   12,845,056
// kbuf  : bf16 [8][4][56][56][32]    6,422,528
// vbuf  : bf16 [8][4][56][56][32]    6,422,528
// xh/xl : bf16 [25088][128]          6,422,528 each   (attn_h/attn_l from natt)
// W splits: qkv hi/lo 98,304 each; proj hi/lo 32,768 each
#define QS_OFF   0
#define K_OFF    12845056
#define V_OFF    (K_OFF + 6422528)
#define XH_OFF   (V_OFF + 6422528)      // attn_h (written by natt)
#define XL_OFF   (XH_OFF + 6422528)     // attn_l
#define WQH_OFF  (XL_OFF + 6422528)
#define WQL_OFF  (WQH_OFF + 98304)
#define WPH_OFF  (WQL_OFF + 98304)
#define WPL_OFF  (WPH_OFF + 32768)

typedef __attribute__((ext_vector_type(8))) short short8v;
typedef __attribute__((ext_vector_type(4))) float f32x4;

__device__ __forceinline__ float blo(unsigned u) { return __uint_as_float(u << 16); }
__device__ __forceinline__ float bhi(unsigned u) { return __uint_as_float(u & 0xffff0000u); }

__device__ __forceinline__ unsigned short f2b(float x) {       // f32 -> bf16 bits, RNE
    unsigned u = __float_as_uint(x);
    unsigned r = (u + 0x7fffu + ((u >> 16) & 1u)) >> 16;
    return (unsigned short)r;
}
__device__ __forceinline__ float b2f(unsigned short s) { return __uint_as_float((unsigned)s << 16); }

// two 4-length fma chains + final add: same FLOPs, ~half the dep latency
__device__ __forceinline__ float dot8t(const float* q8, uint4 k) {
    float s0, s1;
    s0 = q8[0] * blo(k.x); s0 = fmaf(q8[1], bhi(k.x), s0);
    s0 = fmaf(q8[2], blo(k.y), s0); s0 = fmaf(q8[3], bhi(k.y), s0);
    s1 = q8[4] * blo(k.z); s1 = fmaf(q8[5], bhi(k.z), s1);
    s1 = fmaf(q8[6], blo(k.w), s1); s1 = fmaf(q8[7], bhi(k.w), s1);
    return s0 + s1;
}

// quad (4-lane) sum via DPP quad_perm: xor1 = 0xB1, xor2 = 0x4E. VALU-only.
__device__ __forceinline__ float quad_sum(float x) {
    x += __int_as_float(__builtin_amdgcn_update_dpp(0, __float_as_int(x), 0xB1, 0xF, 0xF, true));
    x += __int_as_float(__builtin_amdgcn_update_dpp(0, __float_as_int(x), 0x4E, 0xF, 0xF, true));
    return x;
}

// ---------------------------------------------------------------------------
// Pre-split (weights only): W_qkv 12288 f4 + W_proj 4096 f4 = 16384.
// ---------------------------------------------------------------------------
__global__ __launch_bounds__(256) void split_k(
    const float* __restrict__ wq, const float* __restrict__ wp,
    unsigned short* __restrict__ wqh, unsigned short* __restrict__ wql,
    unsigned short* __restrict__ wph, unsigned short* __restrict__ wpl)
{
    int idx = blockIdx.x * 256 + threadIdx.x;
    if (idx >= 16384) return;
    const float* src; unsigned short *dh, *dl; int off;
    if (idx < 12288) { src = wq; dh = wqh; dl = wql; off = idx; }
    else             { src = wp; dh = wph; dl = wpl; off = idx - 12288; }
    float4 v = ((const float4*)src)[off];
    ushort4 h, l;
    h.x = f2b(v.x); l.x = f2b(v.x - b2f(h.x));
    h.y = f2b(v.y); l.y = f2b(v.y - b2f(h.y));
    h.z = f2b(v.z); l.z = f2b(v.z - b2f(h.z));
    h.w = f2b(v.w); l.w = f2b(v.w - b2f(h.w));
    ((ushort4*)dh)[off] = h;
    ((ushort4*)dl)[off] = l;
}

// ---------------------------------------------------------------------------
// Fused-N MFMA GEMM (bf16x2 split), unchanged from rounds 7/8.
// grid = 392 m-blocks; A-tile staged once; NPH n-phases restage 32 KB B-tile.
//  SELQKV=1: NPH=6 (q/k/v scatter epilogue), A = f32 x split in-kernel.
//  SELQKV=0: NPH=2 (f32 rows), A = attn hi/lo bf16.
// ---------------------------------------------------------------------------
template <int SELQKV>
__global__ __launch_bounds__(256, 2) void gemm_fused(
    const float* __restrict__ Af32,
    const unsigned short* __restrict__ Axh, const unsigned short* __restrict__ Axl,
    const unsigned short* __restrict__ Bgh, const unsigned short* __restrict__ Bgl,
    const float* __restrict__ bias,
    float* __restrict__ outq, unsigned short* __restrict__ outk,
    unsigned short* __restrict__ outv, float* __restrict__ outp)
{
    __shared__ unsigned short sAh[64 * 128];
    __shared__ unsigned short sAl[64 * 128];
    __shared__ unsigned short sBh[64 * 128];
    __shared__ unsigned short sBl[64 * 128];

    const int tid = threadIdx.x;
    const int m0 = blockIdx.x * 64;
    constexpr int NPH = SELQKV ? 6 : 2;

    // ---- stage A once ----
    if constexpr (SELQKV) {
#pragma unroll
        for (int it = 0; it < 8; ++it) {
            int idx = tid + it * 256;          // 0..2047 float4 chunks
            int row = idx >> 5;                // 0..63
            int c4  = idx & 31;
            float4 a = *(const float4*)(Af32 + (size_t)(m0 + row) * 128 + c4 * 4);
            int byte = (row * 256 + c4 * 8) ^ ((row & 7) << 4);
            ushort4 h, l;
            h.x = f2b(a.x); l.x = f2b(a.x - b2f(h.x));
            h.y = f2b(a.y); l.y = f2b(a.y - b2f(h.y));
            h.z = f2b(a.z); l.z = f2b(a.z - b2f(h.z));
            h.w = f2b(a.w); l.w = f2b(a.w - b2f(h.w));
            *(ushort4*)((char*)sAh + byte) = h;
            *(ushort4*)((char*)sAl + byte) = l;
        }
    } else {
#pragma unroll
        for (int it = 0; it < 4; ++it) {
            int chunk = it * 256 + tid;        // 0..1023
            int row = chunk >> 4, c16 = chunk & 15;
            int byte = (row * 256 + c16 * 16) ^ ((row & 7) << 4);
            size_t ga = (size_t)(m0 + row) * 128 + c16 * 8;
            *(uint4*)((char*)sAh + byte) = *(const uint4*)(Axh + ga);
            *(uint4*)((char*)sAl + byte) = *(const uint4*)(Axl + ga);
        }
    }

    const int lane = tid & 63;
    const int w  = tid >> 6;
    const int wr = w >> 1, wc = w & 1;       // 2x2 waves -> 64x64
    const int fr  = lane & 15;
    const int kqb = (lane >> 4) * 16;        // k byte offset within 64B group
    const int cl = lane & 15;
    const int rq = lane >> 4;

    for (int ph = 0; ph < NPH; ++ph) {
        const int n0 = ph * 64;
        if (ph > 0) __syncthreads();         // prior mfma reads done before B overwrite
#pragma unroll
        for (int it = 0; it < 4; ++it) {
            int chunk = it * 256 + tid;      // 0..1023
            int row = chunk >> 4, c16 = chunk & 15;
            int byte = (row * 256 + c16 * 16) ^ ((row & 7) << 4);
            size_t gb = (size_t)(n0 + row) * 128 + c16 * 8;
            *(uint4*)((char*)sBh + byte) = *(const uint4*)(Bgh + gb);
            *(uint4*)((char*)sBl + byte) = *(const uint4*)(Bgl + gb);
        }
        __syncthreads();

        f32x4 acc[2][2];
#pragma unroll
        for (int i = 0; i < 2; ++i)
#pragma unroll
            for (int j = 0; j < 2; ++j) acc[i][j] = (f32x4){0.f, 0.f, 0.f, 0.f};

#pragma unroll
        for (int ks = 0; ks < 4; ++ks) {
            short8v ah[2], al[2], bh[2], bl[2];
#pragma unroll
            for (int mi = 0; mi < 2; ++mi) {
                int row = wr * 32 + mi * 16 + fr;
                int byte = (row * 256 + ks * 64 + kqb) ^ ((row & 7) << 4);
                ah[mi] = *(const short8v*)((const char*)sAh + byte);
                al[mi] = *(const short8v*)((const char*)sAl + byte);
            }
#pragma unroll
            for (int ni = 0; ni < 2; ++ni) {
                int row = wc * 32 + ni * 16 + fr;
                int byte = (row * 256 + ks * 64 + kqb) ^ ((row & 7) << 4);
                bh[ni] = *(const short8v*)((const char*)sBh + byte);
                bl[ni] = *(const short8v*)((const char*)sBl + byte);
            }
#pragma unroll
            for (int mi = 0; mi < 2; ++mi)
#pragma unroll
                for (int ni = 0; ni < 2; ++ni) {
                    acc[mi][ni] = __builtin_amdgcn_mfma_f32_16x16x32_bf16(ah[mi], bh[ni], acc[mi][ni], 0, 0, 0);
                    acc[mi][ni] = __builtin_amdgcn_mfma_f32_16x16x32_bf16(ah[mi], bl[ni], acc[mi][ni], 0, 0, 0);
                    acc[mi][ni] = __builtin_amdgcn_mfma_f32_16x16x32_bf16(al[mi], bh[ni], acc[mi][ni], 0, 0, 0);
                }
        }

        // ---- epilogue: C/D layout col=lane&15, row=4*(lane>>4)+reg ----
#pragma unroll
        for (int mi = 0; mi < 2; ++mi) {
#pragma unroll
            for (int reg = 0; reg < 4; ++reg) {
                int m = m0 + wr * 32 + mi * 16 + rq * 4 + reg;
                if constexpr (SELQKV) {
                    int b = m / 3136;
                    int r = m - b * 3136;
                    int y = r / 56;
                    int x = r - y * 56;
#pragma unroll
                    for (int ni = 0; ni < 2; ++ni) {
                        int nn = n0 + wc * 32 + ni * 16 + cl;   // 0..383
                        float val = acc[mi][ni][reg] + bias[nn];
                        int sel = nn >> 7;                      // 0=q 1=k 2=v
                        int nl = nn & 127;
                        int h = nl >> 5, d = nl & 31;
                        size_t oi = ((size_t)((b * NH + h) * 3136) + y * 56 + x) * 32 + d;
                        if (sel == 0)      outq[oi] = val * SCALE;
                        else if (sel == 1) outk[oi] = f2b(val);
                        else               outv[oi] = f2b(val);
                    }
                } else {
#pragma unroll
                    for (int ni = 0; ni < 2; ++ni) {
                        int nn = n0 + wc * 32 + ni * 16 + cl;
                        outp[(size_t)m * 128 + nn] = acc[mi][ni][reg] + bias[nn];
                    }
                }
            }
        }
    }
}

// ---------------------------------------------------------------------------
// Neighborhood attention v6: 4 threads per (pixel,head) d-chunk split
// (round-8 geometry: 256 thr, 8x8 tile, halo 14x14, grid 49x4x8), with:
//  * V unpacked to f32 in LDS at staging -> PV axpy is 8 plain fmaf/key
//    (removes 8 blo/bhi unpacks per key from the hot loop).
//    Layout vfs[4][196*8+4]: c-major sections, 4-word section pad ->
//    section stride 1572 % 32 = 4, pixel stride 8: each wave b128 read is a
//    uniform 8-deep bank spread (= conflict-free b128 rate); 16B-aligned.
//  * K stays bf16 [pix][c] (uniform banks) -> LDS 12.25 + 24.56 = 36.8 KB
//    -> 4 blocks/CU = 16 waves/CU.
//  * dot as two 4-chains + add (shorter dependency chain).
//  * q global load hoisted above staging (overlaps HBM latency).
// Numerics: v f32 = exact b2f of same bf16 -> products identical; only dot
// summation order changes (ulp-level).
// ---------------------------------------------------------------------------
__global__ __launch_bounds__(256, 4) void natt_k(
    const float* __restrict__ qs, const unsigned short* __restrict__ kb,
    const unsigned short* __restrict__ vb, const float* __restrict__ rpb,
    unsigned short* __restrict__ attn_h, unsigned short* __restrict__ attn_l)
{
    __shared__ uint4 ks[196 * 4];                    // K bf16 [pix][c], 12544 B
    __shared__ __align__(16) float vfs[4][1572];     // V f32 c-sections, 25152 B

    const int tid = threadIdx.x;
    const int b = blockIdx.z, h = blockIdx.y;
    const int tyy = blockIdx.x / 7, txx = blockIdx.x - tyy * 7;  // 7x7 tiles
    const int y0 = tyy * 8, x0 = txx * 8;
    const int bh = b * NH + h;

    const int p = tid >> 2, c = tid & 3;   // quads 4-aligned -> DPP partners co-active
    const int py = p >> 3;
    const int pxx = p & 7;

    // hoisted q load (independent of staging; overlaps global latency)
    float q[8];
    {
        const float4* qgp = (const float4*)(qs +
            ((size_t)(bh * 3136) + (y0 + py) * 56 + (x0 + pxx)) * 32 + c * 8);
        float4 t0 = qgp[0], t1 = qgp[1];
        q[0] = t0.x; q[1] = t0.y; q[2] = t0.z; q[3] = t0.w;
        q[4] = t1.x; q[5] = t1.y; q[6] = t1.z; q[7] = t1.w;
    }

    const uint4* kg = (const uint4*)kb;  // 4 uint4 per pixel (32 bf16)
    const uint4* vg = (const uint4*)vb;
    for (int idx = tid; idx < 784; idx += 256) {   // 196 pix * 4 chunks
        int pix = idx >> 2, cc = idx & 3;
        int i = pix / 14;
        int j = pix - i * 14;
        int y = y0 + i - PAD;
        int x = x0 + j - PAD;
        uint4 zk = make_uint4(0u, 0u, 0u, 0u);
        uint4 zv = make_uint4(0u, 0u, 0u, 0u);
        if ((unsigned)y < 56u && (unsigned)x < 56u) {
            int g = ((bh * 3136) + y * 56 + x) * 4 + cc;
            zk = kg[g];
            zv = vg[g];
        }
        ks[idx] = zk;
        float4 f0, f1;
        f0.x = blo(zv.x); f0.y = bhi(zv.x); f0.z = blo(zv.y); f0.w = bhi(zv.y);
        f1.x = blo(zv.z); f1.y = bhi(zv.z); f1.z = blo(zv.w); f1.w = bhi(zv.w);
        float* vd = &vfs[cc][pix * 8];
        *(float4*)(vd)     = f0;
        *(float4*)(vd + 4) = f1;
    }
    __syncthreads();

    float acc[8];
#pragma unroll
    for (int d = 0; d < 8; ++d) acc[d] = 0.f;
    float l = 0.f;

    const float* rph = rpb + h * 49;       // uniform index -> scalar loads
    const float* vbase = &vfs[c][0];

#pragma unroll
    for (int dy = 0; dy < 7; ++dy) {
        int rowpix = (py + dy) * 14 + pxx;
#pragma unroll
        for (int dx = 0; dx < 7; ++dx) {
            int pix = rowpix + dx;
            float s  = dot8t(q, ks[pix * 4 + c]);
            float sf = quad_sum(s) + rph[dy * 7 + dx];
            float e  = __expf(sf);
            l += e;
            const float* vv = vbase + pix * 8;
            float4 v0 = *(const float4*)(vv);
            float4 v1 = *(const float4*)(vv + 4);
            acc[0] = fmaf(e, v0.x, acc[0]); acc[1] = fmaf(e, v0.y, acc[1]);
            acc[2] = fmaf(e, v0.z, acc[2]); acc[3] = fmaf(e, v0.w, acc[3]);
            acc[4] = fmaf(e, v1.x, acc[4]); acc[5] = fmaf(e, v1.y, acc[5]);
            acc[6] = fmaf(e, v1.z, acc[6]); acc[7] = fmaf(e, v1.w, acc[7]);
        }
    }

    float rl = 1.0f / l;

    // pack 8 dims -> (hi, lo) bf16 uint4, single b128 store each
    unsigned short hv[8], lv[8];
#pragma unroll
    for (int d = 0; d < 8; ++d) {
        float val = acc[d] * rl;
        hv[d] = f2b(val);
        lv[d] = f2b(val - b2f(hv[d]));
    }
    uint4 uh, ul;
    uh.x = (unsigned)hv[0] | ((unsigned)hv[1] << 16);
    uh.y = (unsigned)hv[2] | ((unsigned)hv[3] << 16);
    uh.z = (unsigned)hv[4] | ((unsigned)hv[5] << 16);
    uh.w = (unsigned)hv[6] | ((unsigned)hv[7] << 16);
    ul.x = (unsigned)lv[0] | ((unsigned)lv[1] << 16);
    ul.y = (unsigned)lv[2] | ((unsigned)lv[3] << 16);
    ul.z = (unsigned)lv[4] | ((unsigned)lv[5] << 16);
    ul.w = (unsigned)lv[6] | ((unsigned)lv[7] << 16);

    size_t base = ((size_t)(b * 3136) + (y0 + py) * 56 + (x0 + pxx)) * 128 + h * 32 + c * 8;
    *(uint4*)(attn_h + base) = uh;
    *(uint4*)(attn_l + base) = ul;
}

extern "C" void kernel_launch(void* const* d_in, const int* in_sizes, int n_in,
                              void* d_out, int out_size, void* d_ws, size_t ws_size,
                              hipStream_t stream)
{
    const float* x     = (const float*)d_in[0];
    const float* Wqkv  = (const float*)d_in[1];
    const float* bqkv  = (const float*)d_in[2];
    const float* rpb   = (const float*)d_in[3];
    const float* Wproj = (const float*)d_in[4];
    const float* bproj = (const float*)d_in[5];
    float* out = (float*)d_out;

    char* ws = (char*)d_ws;
    float*          qsb  = (float*)(ws + QS_OFF);
    unsigned short* kbuf = (unsigned short*)(ws + K_OFF);
    unsigned short* vbuf = (unsigned short*)(ws + V_OFF);
    unsigned short* xh   = (unsigned short*)(ws + XH_OFF);   // attn_h (from natt)
    unsigned short* xl   = (unsigned short*)(ws + XL_OFF);   // attn_l
    unsigned short* wqh  = (unsigned short*)(ws + WQH_OFF);
    unsigned short* wql  = (unsigned short*)(ws + WQL_OFF);
    unsigned short* wph  = (unsigned short*)(ws + WPH_OFF);
    unsigned short* wpl  = (unsigned short*)(ws + WPL_OFF);

    // 0) split weights into (hi,lo) bf16 (tiny)
    split_k<<<64, 256, 0, stream>>>(Wqkv, Wproj, wqh, wql, wph, wpl);

    // 1) QKV projection: 392 m-blocks, 6 internal n-phases (A staged once)
    gemm_fused<1><<<392, 256, 0, stream>>>(x, nullptr, nullptr, wqh, wql, bqkv,
                                           qsb, kbuf, vbuf, nullptr);

    // 2) neighborhood attention: 49 tiles x 4 heads x 8 batch, 256 thr/blk
    natt_k<<<dim3(49, NH, 8), 256, 0, stream>>>(qsb, kbuf, vbuf, rpb, xh, xl);

    // 3) output projection: 392 m-blocks, 2 internal n-phases
    gemm_fused<0><<<392, 256, 0, stream>>>(nullptr, xh, xl, wph, wpl, bproj,
                                           nullptr, nullptr, nullptr, out);
}